// Round 2
// baseline (4164.125 us; speedup 1.0000x reference)
//
#include <hip/hip_runtime.h>
#include <stdint.h>
#include <stddef.h>

// ---------- types / helpers ----------
typedef __attribute__((ext_vector_type(8))) short  short8;   // 8 bf16 (4 VGPRs)
typedef __attribute__((ext_vector_type(4))) float  floatx4;  // MFMA acc

static __device__ __forceinline__ float b2f(uint16_t h) {
  union { uint32_t u; float f; } v; v.u = ((uint32_t)h) << 16; return v.f;
}
static __device__ __forceinline__ uint16_t f2b(float f) {
  union { float f; uint32_t u; } v; v.f = f;
  uint32_t u = v.u;
  uint32_t r = u + 0x7FFFu + ((u >> 16) & 1u);   // RNE
  return (uint16_t)(r >> 16);
}
static __device__ __forceinline__ float sigm(float x)  { return 1.0f / (1.0f + __expf(-x)); }
static __device__ __forceinline__ float tanh_f(float x){ return 1.0f - 2.0f / (1.0f + __expf(2.0f * x)); }

static __device__ __forceinline__ floatx4 mfma16(short8 a, short8 b, floatx4 c) {
  return __builtin_amdgcn_mfma_f32_16x16x32_bf16(a, b, c, 0, 0, 0);
}
// convert 8 consecutive f32 -> bf16 short8 (RNE)
static __device__ __forceinline__ short8 cvt8(const float* p) {
  short8 r;
  #pragma unroll
  for (int i = 0; i < 8; ++i) r[i] = (short)f2b(p[i]);
  return r;
}

#define H 256
#define FH 1024         // 4*H
#define BATCH 32
#define TSEQ 512
#define DSTEPS 64

// =====================================================================
// Phase A: Xg[16384 x 1024] = A[16384 x 1024](f32) @ W[1024 x 1024]^T(f32) + bias
// split-bf16: A = Ah + Al, W = Wh + Wl; acc += Ah*Wh + Ah*Wl + Al*Wh (fp32-accurate)
// 64x64 tile, 256 threads (4 waves 2x2), BK=32.
// =====================================================================
__global__ __launch_bounds__(256) void gemm_xw(
    const float* __restrict__ A, const float* __restrict__ W,
    const float* __restrict__ bias, void* __restrict__ Cout, int out_f32)
{
  const int K = 1024, N = 1024;
  __shared__ uint16_t Ah[64 * 40], Al[64 * 40];
  __shared__ uint16_t Wh[64 * 40], Wl[64 * 40];
  const int m0 = blockIdx.x * 64;
  const int n0 = blockIdx.y * 64;
  const int tid = threadIdx.x;
  const int lane = tid & 63, w = tid >> 6;
  const int wm = w & 1, wn = w >> 1;
  const int l15 = lane & 15, q4 = lane >> 4;
  const int ldrow = tid >> 2, ldk = (tid & 3) * 8;

  floatx4 acc[2][2];
  for (int i = 0; i < 2; ++i) for (int j = 0; j < 2; ++j) acc[i][j] = (floatx4){0.f,0.f,0.f,0.f};

  for (int kb = 0; kb < K; kb += 32) {
    float aa[8], ww[8];
    {
      const float4* ap = (const float4*)(A + (size_t)(m0 + ldrow) * K + kb + ldk);
      const float4* wp = (const float4*)(W + (size_t)(n0 + ldrow) * K + kb + ldk);
      *(float4*)(aa) = ap[0]; *(float4*)(aa + 4) = ap[1];
      *(float4*)(ww) = wp[0]; *(float4*)(ww + 4) = wp[1];
    }
    short8 ah, al, wh, wl;
    #pragma unroll
    for (int i = 0; i < 8; ++i) {
      uint16_t h = f2b(aa[i]); ah[i] = (short)h; al[i] = (short)f2b(aa[i] - b2f(h));
      uint16_t g = f2b(ww[i]); wh[i] = (short)g; wl[i] = (short)f2b(ww[i] - b2f(g));
    }
    __syncthreads();
    *(short8*)(Ah + ldrow * 40 + ldk) = ah;
    *(short8*)(Al + ldrow * 40 + ldk) = al;
    *(short8*)(Wh + ldrow * 40 + ldk) = wh;
    *(short8*)(Wl + ldrow * 40 + ldk) = wl;
    __syncthreads();
    short8 afh[2], afl[2], bfh[2], bfl[2];
    #pragma unroll
    for (int mt = 0; mt < 2; ++mt) {
      afh[mt] = *(const short8*)(Ah + (wm * 32 + mt * 16 + l15) * 40 + q4 * 8);
      afl[mt] = *(const short8*)(Al + (wm * 32 + mt * 16 + l15) * 40 + q4 * 8);
    }
    #pragma unroll
    for (int nt = 0; nt < 2; ++nt) {
      bfh[nt] = *(const short8*)(Wh + (wn * 32 + nt * 16 + l15) * 40 + q4 * 8);
      bfl[nt] = *(const short8*)(Wl + (wn * 32 + nt * 16 + l15) * 40 + q4 * 8);
    }
    #pragma unroll
    for (int mt = 0; mt < 2; ++mt)
      #pragma unroll
      for (int nt = 0; nt < 2; ++nt) {
        acc[mt][nt] = mfma16(afh[mt], bfh[nt], acc[mt][nt]);
        acc[mt][nt] = mfma16(afh[mt], bfl[nt], acc[mt][nt]);
        acc[mt][nt] = mfma16(afl[mt], bfh[nt], acc[mt][nt]);
      }
  }
  #pragma unroll
  for (int mt = 0; mt < 2; ++mt)
    #pragma unroll
    for (int nt = 0; nt < 2; ++nt) {
      const int col = n0 + wn * 32 + nt * 16 + l15;
      const float bv = bias[col];
      #pragma unroll
      for (int r = 0; r < 4; ++r) {
        const int row = m0 + wm * 32 + mt * 16 + q4 * 4 + r;
        const float v = acc[mt][nt][r] + bv;
        if (out_f32) ((float*)Cout)[(size_t)row * N + col] = v;
        else         ((uint16_t*)Cout)[(size_t)row * N + col] = f2b(v);
      }
    }
}

// =====================================================================
// Phase B: encoder recurrence. 16 WGs: d = blk>>3 (dir), q = blk&7.
// WG owns j in [q*32, q*32+32), all 4 gates (128 rows of Whh) in registers.
// D[gate j][batch] = Whh_slice(bf16) @ h^T(bf16); gates += Xg (f32); c,h in f32.
// h exchanged via agent-scope L2/IF with per-step release counters.
// =====================================================================
__global__ __launch_bounds__(256, 1) void enc_rnn(
    const void* __restrict__ XgF, const void* __restrict__ XgB, int xg_f32,
    const float* __restrict__ WhhF, const float* __restrict__ WhhB,
    uint16_t* __restrict__ hpub,   // [2 dir][2 parity][32][256] bf16
    uint32_t* __restrict__ cnt,    // [2 dir][512]
    uint16_t* __restrict__ hfin,   // [2][32][256] bf16
    float*    __restrict__ cfin)   // [2][32][256] f32
{
  const int d = blockIdx.x >> 3, q = blockIdx.x & 7;
  const void*  Xg  = d ? XgB : XgF;
  const float* Whh = d ? WhhB : WhhF;
  uint16_t* hp = hpub + d * (2 * BATCH * H);
  uint32_t* cn = cnt + d * TSEQ;
  const int jOff = q * 32;
  const int tid = threadIdx.x, lane = tid & 63, w = tid >> 6;
  const int tt = w & 1, nt = w >> 1, l15 = lane & 15, q4 = lane >> 4;
  const int b = nt * 16 + l15;
  const int jg = jOff + tt * 16 + q4 * 4;     // 4 consecutive j's per lane

  __shared__ uint16_t hS[32 * 264];           // h tile (bf16), row stride 264
  __shared__ float    xgS[32 * 132];          // this step's x-gate slice (f32)

  // A-frags (weights) resident in registers: [gate][kstep]
  short8 Af[4][8];
  #pragma unroll
  for (int g = 0; g < 4; ++g) {
    const int grow = g * H + jOff + tt * 16 + l15;
    #pragma unroll
    for (int ks = 0; ks < 8; ++ks)
      Af[g][ks] = cvt8(Whh + (size_t)grow * H + ks * 32 + q4 * 8);
  }
  for (int i = tid; i < 32 * 264; i += 256) hS[i] = 0;

  float cc[4] = {0.f, 0.f, 0.f, 0.f};
  union HV { uint16_t u16[4]; unsigned long long u64; } hv; hv.u64 = 0ull;
  const int rb = tid >> 3, seg = tid & 7;
  const int cp = seg * 16;                    // [0,128) slice column base
  const int gge = cp >> 5, jj = cp & 31;

  for (int s = 0; s < TSEQ; ++s) {
    const int t = d ? (TSEQ - 1 - s) : s;
    // issue this step's Xg loads early (global -> regs)
    float xv[16];
    {
      const size_t base = (size_t)(t * BATCH + rb) * FH + gge * H + jOff + jj;
      if (xg_f32) {
        const float* xs = (const float*)Xg + base;
        #pragma unroll
        for (int i = 0; i < 16; ++i) xv[i] = xs[i];
      } else {
        const uint16_t* xs = (const uint16_t*)Xg + base;
        #pragma unroll
        for (int i = 0; i < 16; ++i) xv[i] = b2f(xs[i]);
      }
    }

    if (s > 0) {
      if (tid == 0) {
        while (__hip_atomic_load(&cn[s - 1], __ATOMIC_ACQUIRE, __HIP_MEMORY_SCOPE_AGENT) < 8u)
          __builtin_amdgcn_s_sleep(4);
      }
      __syncthreads();
      const unsigned long long* ps =
          (const unsigned long long*)(hp + (s & 1) * (BATCH * H) + rb * H + seg * 32);
      unsigned long long tmp[8];
      #pragma unroll
      for (int i = 0; i < 8; ++i)
        tmp[i] = __hip_atomic_load(ps + i, __ATOMIC_RELAXED, __HIP_MEMORY_SCOPE_AGENT);
      #pragma unroll
      for (int i = 0; i < 8; ++i)
        *(unsigned long long*)(hS + rb * 264 + seg * 32 + i * 4) = tmp[i];
    }
    #pragma unroll
    for (int i = 0; i < 16; ++i) xgS[rb * 132 + cp + i] = xv[i];
    __syncthreads();

    floatx4 a0 = {0.f,0.f,0.f,0.f}, a1 = a0, a2 = a0, a3 = a0;
    #pragma unroll
    for (int ks = 0; ks < 8; ++ks) {
      short8 bfv = *(const short8*)(hS + b * 264 + ks * 32 + q4 * 8);
      a0 = mfma16(Af[0][ks], bfv, a0);
      a1 = mfma16(Af[1][ks], bfv, a1);
      a2 = mfma16(Af[2][ks], bfv, a2);
      a3 = mfma16(Af[3][ks], bfv, a3);
    }
    #pragma unroll
    for (int r = 0; r < 4; ++r) {
      const int jl = tt * 16 + q4 * 4 + r;
      const float gi = a0[r] + xgS[b * 132 +      jl];
      const float gf = a1[r] + xgS[b * 132 + 32 + jl];
      const float gc = a2[r] + xgS[b * 132 + 64 + jl];
      const float go = a3[r] + xgS[b * 132 + 96 + jl];
      const float cn2 = sigm(gf) * cc[r] + sigm(gi) * tanh_f(gc);
      cc[r] = cn2;
      hv.u16[r] = f2b(sigm(go) * tanh_f(cn2));
    }
    *(unsigned long long*)(hp + ((s + 1) & 1) * (BATCH * H) + b * H + jg) = hv.u64;
    __threadfence();
    __syncthreads();
    if (tid == 0)
      __hip_atomic_fetch_add(&cn[s], 1u, __ATOMIC_RELEASE, __HIP_MEMORY_SCOPE_AGENT);
  }
  #pragma unroll
  for (int r = 0; r < 4; ++r) {
    hfin[d * (BATCH * H) + b * H + jg + r] = hv.u16[r];
    cfin[d * (BATCH * H) + b * H + jg + r] = cc[r];
  }
}

// =====================================================================
// Phase C: decoder, 2 layers x 64 steps. 16 WGs: L = blk>>3, q = blk&7.
// K = 512 = [x | h] bf16. layer0: x = h1[t-1] (0 at t=0), h/c init = fwd enc state.
// layer1: x = h0[t], h/c init = bwd enc state. h1 kept bf16 (exchange) + f32 (proj).
// =====================================================================
__global__ __launch_bounds__(256, 1) void dec_rnn(
    const float* __restrict__ Wih0, const float* __restrict__ Whh0, const float* __restrict__ bb0,
    const float* __restrict__ Wih1, const float* __restrict__ Whh1, const float* __restrict__ bb1,
    const uint16_t* __restrict__ hfin, const float* __restrict__ cfin,
    uint16_t* __restrict__ h0pub,   // [64][32][256] bf16
    uint16_t* __restrict__ h1hist,  // [64][32][256] bf16
    float*    __restrict__ h1f,     // [64][32][256] f32
    uint32_t* __restrict__ cnt0, uint32_t* __restrict__ cnt1)
{
  const int L = blockIdx.x >> 3, q = blockIdx.x & 7;
  const float* Wih = L ? Wih1 : Wih0;
  const float* Whh = L ? Whh1 : Whh0;
  const float* bs  = L ? bb1 : bb0;
  const int jOff = q * 32;
  const int tid = threadIdx.x, lane = tid & 63, w = tid >> 6;
  const int tt = w & 1, nt = w >> 1, l15 = lane & 15, q4 = lane >> 4;
  const int b = nt * 16 + l15;
  const int jg = jOff + tt * 16 + q4 * 4;

  __shared__ uint16_t xhS[32 * 528];   // cols 0..255 x-part, 256..511 h-part (bf16)

  short8 Af[4][16];
  #pragma unroll
  for (int g = 0; g < 4; ++g) {
    const int grow = g * H + jOff + tt * 16 + l15;
    #pragma unroll
    for (int ks = 0; ks < 8; ++ks) {
      Af[g][ks]     = cvt8(Wih + (size_t)grow * H + ks * 32 + q4 * 8);
      Af[g][8 + ks] = cvt8(Whh + (size_t)grow * H + ks * 32 + q4 * 8);
    }
  }
  float brg[4][4];
  #pragma unroll
  for (int g = 0; g < 4; ++g)
    #pragma unroll
    for (int r = 0; r < 4; ++r)
      brg[g][r] = bs[g * H + jOff + tt * 16 + q4 * 4 + r];

  float cc[4];
  #pragma unroll
  for (int r = 0; r < 4; ++r) cc[r] = cfin[L * (BATCH * H) + b * H + jg + r];

  const int rb = tid >> 3, seg = tid & 7;
  union HV { uint16_t u16[4]; unsigned long long u64; } hv; hv.u64 = 0ull;

  for (int t = 0; t < DSTEPS; ++t) {
    if (tid == 0) {
      if (L == 0) {
        if (t > 0) {
          while (__hip_atomic_load(&cnt1[t - 1], __ATOMIC_ACQUIRE, __HIP_MEMORY_SCOPE_AGENT) < 8u)
            __builtin_amdgcn_s_sleep(4);
          while (__hip_atomic_load(&cnt0[t - 1], __ATOMIC_ACQUIRE, __HIP_MEMORY_SCOPE_AGENT) < 8u)
            __builtin_amdgcn_s_sleep(4);
        }
      } else {
        if (t > 0) {
          while (__hip_atomic_load(&cnt1[t - 1], __ATOMIC_ACQUIRE, __HIP_MEMORY_SCOPE_AGENT) < 8u)
            __builtin_amdgcn_s_sleep(4);
        }
        while (__hip_atomic_load(&cnt0[t], __ATOMIC_ACQUIRE, __HIP_MEMORY_SCOPE_AGENT) < 8u)
          __builtin_amdgcn_s_sleep(4);
      }
    }
    __syncthreads();
    {
      unsigned long long tx[8], th[8];
      if (L == 0 && t == 0) {
        #pragma unroll
        for (int i = 0; i < 8; ++i) tx[i] = 0ull;
      } else {
        const uint16_t* xp = (L == 0) ? (h1hist + (size_t)(t - 1) * (BATCH * H))
                                      : (h0pub + (size_t)t * (BATCH * H));
        const unsigned long long* ps = (const unsigned long long*)(xp + rb * H + seg * 32);
        #pragma unroll
        for (int i = 0; i < 8; ++i)
          tx[i] = __hip_atomic_load(ps + i, __ATOMIC_RELAXED, __HIP_MEMORY_SCOPE_AGENT);
      }
      const uint16_t* hp2 = (t == 0) ? (hfin + L * (BATCH * H))
                    : ((L == 0) ? (h0pub + (size_t)(t - 1) * (BATCH * H))
                                : (h1hist + (size_t)(t - 1) * (BATCH * H)));
      const unsigned long long* ph = (const unsigned long long*)(hp2 + rb * H + seg * 32);
      #pragma unroll
      for (int i = 0; i < 8; ++i)
        th[i] = __hip_atomic_load(ph + i, __ATOMIC_RELAXED, __HIP_MEMORY_SCOPE_AGENT);
      #pragma unroll
      for (int i = 0; i < 8; ++i)
        *(unsigned long long*)(xhS + rb * 528 + seg * 32 + i * 4) = tx[i];
      #pragma unroll
      for (int i = 0; i < 8; ++i)
        *(unsigned long long*)(xhS + rb * 528 + 256 + seg * 32 + i * 4) = th[i];
    }
    __syncthreads();

    floatx4 a0 = {0.f,0.f,0.f,0.f}, a1 = a0, a2 = a0, a3 = a0;
    #pragma unroll
    for (int ks = 0; ks < 16; ++ks) {
      short8 bfv = *(const short8*)(xhS + b * 528 + ks * 32 + q4 * 8);
      a0 = mfma16(Af[0][ks], bfv, a0);
      a1 = mfma16(Af[1][ks], bfv, a1);
      a2 = mfma16(Af[2][ks], bfv, a2);
      a3 = mfma16(Af[3][ks], bfv, a3);
    }
    float hval[4];
    #pragma unroll
    for (int r = 0; r < 4; ++r) {
      const float gi = a0[r] + brg[0][r];
      const float gf = a1[r] + brg[1][r];
      const float gc = a2[r] + brg[2][r];
      const float go = a3[r] + brg[3][r];
      const float cn2 = sigm(gf) * cc[r] + sigm(gi) * tanh_f(gc);
      cc[r] = cn2;
      hval[r] = sigm(go) * tanh_f(cn2);
      hv.u16[r] = f2b(hval[r]);
    }
    uint16_t* dst = (L ? h1hist : h0pub) + (size_t)t * (BATCH * H) + b * H + jg;
    *(unsigned long long*)dst = hv.u64;
    if (L == 1) {
      float* df = h1f + (size_t)t * (BATCH * H) + b * H + jg;
      #pragma unroll
      for (int r = 0; r < 4; ++r) df[r] = hval[r];
    }
    __threadfence();
    __syncthreads();
    if (tid == 0)
      __hip_atomic_fetch_add(L ? &cnt1[t] : &cnt0[t], 1u, __ATOMIC_RELEASE, __HIP_MEMORY_SCOPE_AGENT);
  }
}

// =====================================================================
// Phase D: ys[t,b,v] = h1f[t,b,:] . lin_W[v,:] + lin_b[v]   (all f32)
// =====================================================================
__global__ __launch_bounds__(256) void out_proj(
    const float* __restrict__ h1f, const float* __restrict__ linW,
    const float* __restrict__ linb, float* __restrict__ out)
{
  const int idx = blockIdx.x * 256 + threadIdx.x;
  if (idx >= DSTEPS * BATCH * 3) return;
  const int v = idx % 3;
  const int tb = idx / 3;
  const float* hrow = h1f + (size_t)tb * H;
  const float* wrow = linW + (size_t)v * H;
  float s = linb[v];
  for (int k = 0; k < H; ++k) s += hrow[k] * wrow[k];
  out[idx] = s;
}

// =====================================================================
extern "C" void kernel_launch(void* const* d_in, const int* in_sizes, int n_in,
                              void* d_out, int out_size, void* d_ws, size_t ws_size,
                              hipStream_t stream) {
  (void)in_sizes; (void)n_in; (void)out_size;
  const float* cnn   = (const float*)d_in[0];
  const float* WihF  = (const float*)d_in[1];
  const float* WhhF  = (const float*)d_in[2];
  const float* bF    = (const float*)d_in[3];
  const float* WihB  = (const float*)d_in[4];
  const float* WhhB  = (const float*)d_in[5];
  const float* bB    = (const float*)d_in[6];
  const float* Wih0  = (const float*)d_in[7];
  const float* Whh0  = (const float*)d_in[8];
  const float* b0    = (const float*)d_in[9];
  const float* Wih1  = (const float*)d_in[10];
  const float* Whh1  = (const float*)d_in[11];
  const float* b1    = (const float*)d_in[12];
  const float* linW  = (const float*)d_in[13];
  const float* linb  = (const float*)d_in[14];

  // ws layout: [XgF | XgB | small buffers]. Xg stored f32 if ws allows, else bf16.
  const size_t XG_ELEMS = (size_t)TSEQ * BATCH * FH;            // 16M elems per dir
  const size_t SMALL    = 4366336;                              // small-buffer region
  const int xg_f32 = (ws_size >= 2 * XG_ELEMS * 4 + SMALL) ? 1 : 0;
  const size_t S = XG_ELEMS * (xg_f32 ? 4 : 2);

  uint8_t* ws = (uint8_t*)d_ws;
  void*     XgF    = (void*)(ws);
  void*     XgB    = (void*)(ws + S);
  uint8_t*  base   = ws + 2 * S;
  uint16_t* hpub   = (uint16_t*)(base);              // 65536 B
  uint16_t* hfin   = (uint16_t*)(base + 65536);      // 32768 B
  float*    cfin   = (float*)(base + 98304);         // 65536 B
  uint16_t* h0pub  = (uint16_t*)(base + 163840);     // 1 MB
  uint16_t* h1hist = (uint16_t*)(base + 1212416);    // 1 MB
  float*    h1f    = (float*)(base + 2260992);       // 2 MB
  uint32_t* cntE   = (uint32_t*)(base + 4358144);    // [2][512] u32
  uint32_t* cnt0   = cntE + 1024;                    // [64]
  uint32_t* cnt1   = cnt0 + 64;                      // [64]

  hipMemsetAsync(base + 4358144, 0, 8192, stream);

  gemm_xw<<<dim3(256, 16), 256, 0, stream>>>(cnn, WihF, bF, XgF, xg_f32);
  gemm_xw<<<dim3(256, 16), 256, 0, stream>>>(cnn, WihB, bB, XgB, xg_f32);
  enc_rnn<<<16, 256, 0, stream>>>(XgF, XgB, xg_f32, WhhF, WhhB, hpub, cntE, hfin, cfin);
  dec_rnn<<<16, 256, 0, stream>>>(Wih0, Whh0, b0, Wih1, Whh1, b1,
                                  hfin, cfin, h0pub, h1hist, h1f, cnt0, cnt1);
  out_proj<<<24, 256, 0, stream>>>(h1f, linW, linb, (float*)d_out);
}

// Round 4
// 2933.257 us; speedup vs baseline: 1.4196x; 1.4196x over previous
//
#include <hip/hip_runtime.h>
#include <stdint.h>
#include <stddef.h>

// ---------- types / helpers ----------
typedef __attribute__((ext_vector_type(8))) short  short8;   // 8 bf16 (4 VGPRs)
typedef __attribute__((ext_vector_type(4))) float  floatx4;  // MFMA acc

static __device__ __forceinline__ float b2f(uint16_t h) {
  union { uint32_t u; float f; } v; v.u = ((uint32_t)h) << 16; return v.f;
}
static __device__ __forceinline__ uint16_t f2b(float f) {
  union { float f; uint32_t u; } v; v.f = f;
  uint32_t u = v.u;
  uint32_t r = u + 0x7FFFu + ((u >> 16) & 1u);   // RNE
  return (uint16_t)(r >> 16);
}
static __device__ __forceinline__ float sigm(float x)  { return 1.0f / (1.0f + __expf(-x)); }
static __device__ __forceinline__ float tanh_f(float x){ return 1.0f - 2.0f / (1.0f + __expf(2.0f * x)); }

static __device__ __forceinline__ floatx4 mfma16(short8 a, short8 b, floatx4 c) {
  return __builtin_amdgcn_mfma_f32_16x16x32_bf16(a, b, c, 0, 0, 0);
}
static __device__ __forceinline__ short8 cvt8(const float* p) {
  short8 r;
  #pragma unroll
  for (int i = 0; i < 8; ++i) r[i] = (short)f2b(p[i]);
  return r;
}
// cross-WG exchange primitives (agent scope; proven correct in round 2)
static __device__ __forceinline__ uint32_t ld_flag_rlx(const uint32_t* p) {
  return __hip_atomic_load(p, __ATOMIC_RELAXED, __HIP_MEMORY_SCOPE_AGENT);
}
static __device__ __forceinline__ void st_flag_rel(uint32_t* p, uint32_t v) {
  __hip_atomic_store(p, v, __ATOMIC_RELEASE, __HIP_MEMORY_SCOPE_AGENT);
}
static __device__ __forceinline__ unsigned long long ld_h64(const unsigned long long* p) {
  return __hip_atomic_load(p, __ATOMIC_RELAXED, __HIP_MEMORY_SCOPE_AGENT);
}
static __device__ __forceinline__ void st_h64(uint16_t* p, unsigned long long v) {
  __hip_atomic_store((unsigned long long*)p, v, __ATOMIC_RELAXED, __HIP_MEMORY_SCOPE_AGENT);
}

#define H 256
#define FH 1024
#define BATCH 32
#define TSEQ 512
#define DSTEPS 64

// =====================================================================
// Phase A GEMM (unchanged — correct since round 2)
// =====================================================================
__global__ __launch_bounds__(256) void gemm_xw(
    const float* __restrict__ A, const float* __restrict__ W,
    const float* __restrict__ bias, void* __restrict__ Cout, int out_f32)
{
  const int K = 1024, N = 1024;
  __shared__ uint16_t Ah[64 * 40], Al[64 * 40];
  __shared__ uint16_t Wh[64 * 40], Wl[64 * 40];
  const int m0 = blockIdx.x * 64;
  const int n0 = blockIdx.y * 64;
  const int tid = threadIdx.x;
  const int lane = tid & 63, w = tid >> 6;
  const int wm = w & 1, wn = w >> 1;
  const int l15 = lane & 15, q4 = lane >> 4;
  const int ldrow = tid >> 2, ldk = (tid & 3) * 8;

  floatx4 acc[2][2];
  for (int i = 0; i < 2; ++i) for (int j = 0; j < 2; ++j) acc[i][j] = (floatx4){0.f,0.f,0.f,0.f};

  for (int kb = 0; kb < K; kb += 32) {
    float aa[8], ww[8];
    {
      const float4* ap = (const float4*)(A + (size_t)(m0 + ldrow) * K + kb + ldk);
      const float4* wp = (const float4*)(W + (size_t)(n0 + ldrow) * K + kb + ldk);
      *(float4*)(aa) = ap[0]; *(float4*)(aa + 4) = ap[1];
      *(float4*)(ww) = wp[0]; *(float4*)(ww + 4) = wp[1];
    }
    short8 ah, al, wh, wl;
    #pragma unroll
    for (int i = 0; i < 8; ++i) {
      uint16_t h = f2b(aa[i]); ah[i] = (short)h; al[i] = (short)f2b(aa[i] - b2f(h));
      uint16_t g = f2b(ww[i]); wh[i] = (short)g; wl[i] = (short)f2b(ww[i] - b2f(g));
    }
    __syncthreads();
    *(short8*)(Ah + ldrow * 40 + ldk) = ah;
    *(short8*)(Al + ldrow * 40 + ldk) = al;
    *(short8*)(Wh + ldrow * 40 + ldk) = wh;
    *(short8*)(Wl + ldrow * 40 + ldk) = wl;
    __syncthreads();
    short8 afh[2], afl[2], bfh[2], bfl[2];
    #pragma unroll
    for (int mt = 0; mt < 2; ++mt) {
      afh[mt] = *(const short8*)(Ah + (wm * 32 + mt * 16 + l15) * 40 + q4 * 8);
      afl[mt] = *(const short8*)(Al + (wm * 32 + mt * 16 + l15) * 40 + q4 * 8);
    }
    #pragma unroll
    for (int nt = 0; nt < 2; ++nt) {
      bfh[nt] = *(const short8*)(Wh + (wn * 32 + nt * 16 + l15) * 40 + q4 * 8);
      bfl[nt] = *(const short8*)(Wl + (wn * 32 + nt * 16 + l15) * 40 + q4 * 8);
    }
    #pragma unroll
    for (int mt = 0; mt < 2; ++mt)
      #pragma unroll
      for (int nt = 0; nt < 2; ++nt) {
        acc[mt][nt] = mfma16(afh[mt], bfh[nt], acc[mt][nt]);
        acc[mt][nt] = mfma16(afh[mt], bfl[nt], acc[mt][nt]);
        acc[mt][nt] = mfma16(afl[mt], bfh[nt], acc[mt][nt]);
      }
  }
  #pragma unroll
  for (int mt = 0; mt < 2; ++mt)
    #pragma unroll
    for (int nt = 0; nt < 2; ++nt) {
      const int col = n0 + wn * 32 + nt * 16 + l15;
      const float bv = bias[col];
      #pragma unroll
      for (int r = 0; r < 4; ++r) {
        const int row = m0 + wm * 32 + mt * 16 + q4 * 4 + r;
        const float v = acc[mt][nt][r] + bv;
        if (out_f32) ((float*)Cout)[(size_t)row * N + col] = v;
        else         ((uint16_t*)Cout)[(size_t)row * N + col] = f2b(v);
      }
    }
}

// =====================================================================
// Phase B: encoder recurrence. Grid = 16 WGs: d = blk>>3, q = blk&7.
// Sync: per-WG flags; producers release-store after syncthreads-drained
// publish; consumers all-lane relaxed-poll then load (in-order issue makes
// the flag->data dependency safe; both are L2-bypassing agent-scope ops).
// =====================================================================
__global__ __launch_bounds__(256, 1) void enc_rnn(
    const void* __restrict__ XgF, const void* __restrict__ XgB, int xg_f32,
    const float* __restrict__ WhhF, const float* __restrict__ WhhB,
    uint16_t* __restrict__ hpub,      // [2 dir][2 parity][32][256] bf16
    uint32_t* __restrict__ encflags,  // [2 dir][512][8]
    uint16_t* __restrict__ hfin, float* __restrict__ cfin)
{
  const int d = blockIdx.x >> 3, q = blockIdx.x & 7;
  const void*  Xg  = d ? XgB : XgF;
  const float* Whh = d ? WhhB : WhhF;
  uint16_t* hp  = hpub + d * (2 * BATCH * H);
  uint32_t* flg = encflags + d * (TSEQ * 8);
  const int jOff = q * 32;
  const int tid = threadIdx.x, lane = tid & 63, w = tid >> 6;
  const int tt = w & 1, nt = w >> 1, l15 = lane & 15, q4 = lane >> 4;
  const int b = nt * 16 + l15;
  const int jg = jOff + tt * 16 + q4 * 4;

  __shared__ uint16_t hS[32 * 264];
  __shared__ float    xgS[32 * 132];

  short8 Af[4][8];
  #pragma unroll
  for (int g = 0; g < 4; ++g) {
    const int grow = g * H + jOff + tt * 16 + l15;
    #pragma unroll
    for (int ks = 0; ks < 8; ++ks)
      Af[g][ks] = cvt8(Whh + (size_t)grow * H + ks * 32 + q4 * 8);
  }
  for (int i = tid; i < 32 * 264; i += 256) hS[i] = 0;

  float cc[4] = {0.f, 0.f, 0.f, 0.f};
  union HV { uint16_t u16[4]; unsigned long long u64; } hv; hv.u64 = 0ull;
  const int rb = tid >> 3, seg = tid & 7;
  const int cp = seg * 16;
  const int gge = cp >> 5, jj = cp & 31;

  for (int s = 0; s < TSEQ; ++s) {
    const int t = d ? (TSEQ - 1 - s) : s;
    // issue this step's Xg loads early
    float xv[16];
    {
      const size_t base = (size_t)(t * BATCH + rb) * FH + gge * H + jOff + jj;
      if (xg_f32) {
        const float* xs = (const float*)Xg + base;
        #pragma unroll
        for (int i = 0; i < 16; ++i) xv[i] = xs[i];
      } else {
        const uint16_t* xs = (const uint16_t*)Xg + base;
        #pragma unroll
        for (int i = 0; i < 16; ++i) xv[i] = b2f(xs[i]);
      }
    }

    if (s > 0) {
      // all-lane relaxed poll of the 8 per-WG flags of step s-1
      const uint32_t* f = flg + (size_t)(s - 1) * 8 + (lane & 7);
      while (!__all(ld_flag_rlx(f) != 0u))
        __builtin_amdgcn_s_sleep(1);
      const unsigned long long* ps =
          (const unsigned long long*)(hp + (s & 1) * (BATCH * H) + rb * H + seg * 32);
      unsigned long long tmp[8];
      #pragma unroll
      for (int i = 0; i < 8; ++i) tmp[i] = ld_h64(ps + i);
      #pragma unroll
      for (int i = 0; i < 8; ++i)
        *(unsigned long long*)(hS + rb * 264 + seg * 32 + i * 4) = tmp[i];
    }
    #pragma unroll
    for (int i = 0; i < 16; ++i) xgS[rb * 132 + cp + i] = xv[i];
    __syncthreads();

    floatx4 a0 = {0.f,0.f,0.f,0.f}, a1 = a0, a2 = a0, a3 = a0;
    #pragma unroll
    for (int ks = 0; ks < 8; ++ks) {
      short8 bfv = *(const short8*)(hS + b * 264 + ks * 32 + q4 * 8);
      a0 = mfma16(Af[0][ks], bfv, a0);
      a1 = mfma16(Af[1][ks], bfv, a1);
      a2 = mfma16(Af[2][ks], bfv, a2);
      a3 = mfma16(Af[3][ks], bfv, a3);
    }
    #pragma unroll
    for (int r = 0; r < 4; ++r) {
      const int jl = tt * 16 + q4 * 4 + r;
      const float gi = a0[r] + xgS[b * 132 +      jl];
      const float gf = a1[r] + xgS[b * 132 + 32 + jl];
      const float gc = a2[r] + xgS[b * 132 + 64 + jl];
      const float go = a3[r] + xgS[b * 132 + 96 + jl];
      const float cn2 = sigm(gf) * cc[r] + sigm(gi) * tanh_f(gc);
      cc[r] = cn2;
      hv.u16[r] = f2b(sigm(go) * tanh_f(cn2));
    }
    st_h64(hp + ((s + 1) & 1) * (BATCH * H) + b * H + jg, hv.u64);
    __syncthreads();                 // waves drain vmcnt(0) before barrier exit
    if (tid == 0) st_flag_rel(flg + (size_t)s * 8 + q, 1u);
  }
  #pragma unroll
  for (int r = 0; r < 4; ++r) {
    hfin[d * (BATCH * H) + b * H + jg + r] = hv.u16[r];   // kernel boundary
    cfin[d * (BATCH * H) + b * H + jg + r] = cc[r];
  }
}

// =====================================================================
// Phase C: decoder, 2 layers x 64 steps. Grid = 16 WGs: L = blk>>3, q = blk&7.
// =====================================================================
__global__ __launch_bounds__(256, 1) void dec_rnn(
    const float* __restrict__ Wih0, const float* __restrict__ Whh0, const float* __restrict__ bb0,
    const float* __restrict__ Wih1, const float* __restrict__ Whh1, const float* __restrict__ bb1,
    const uint16_t* __restrict__ hfin, const float* __restrict__ cfin,
    uint16_t* __restrict__ h0pub, uint16_t* __restrict__ h1hist, float* __restrict__ h1f,
    uint32_t* __restrict__ f0, uint32_t* __restrict__ f1)
{
  const int L = blockIdx.x >> 3, q = blockIdx.x & 7;
  const float* Wih = L ? Wih1 : Wih0;
  const float* Whh = L ? Whh1 : Whh0;
  const float* bs  = L ? bb1 : bb0;
  const int jOff = q * 32;
  const int tid = threadIdx.x, lane = tid & 63, w = tid >> 6;
  const int tt = w & 1, nt = w >> 1, l15 = lane & 15, q4 = lane >> 4;
  const int b = nt * 16 + l15;
  const int jg = jOff + tt * 16 + q4 * 4;

  __shared__ uint16_t xhS[32 * 528];

  short8 Af[4][16];
  #pragma unroll
  for (int g = 0; g < 4; ++g) {
    const int grow = g * H + jOff + tt * 16 + l15;
    #pragma unroll
    for (int ks = 0; ks < 8; ++ks) {
      Af[g][ks]     = cvt8(Wih + (size_t)grow * H + ks * 32 + q4 * 8);
      Af[g][8 + ks] = cvt8(Whh + (size_t)grow * H + ks * 32 + q4 * 8);
    }
  }
  float brg[4][4];
  #pragma unroll
  for (int g = 0; g < 4; ++g)
    #pragma unroll
    for (int r = 0; r < 4; ++r)
      brg[g][r] = bs[g * H + jOff + tt * 16 + q4 * 4 + r];

  float cc[4];
  #pragma unroll
  for (int r = 0; r < 4; ++r) cc[r] = cfin[L * (BATCH * H) + b * H + jg + r];

  const int rb = tid >> 3, seg = tid & 7;
  union HV { uint16_t u16[4]; unsigned long long u64; } hv; hv.u64 = 0ull;

  for (int t = 0; t < DSTEPS; ++t) {
    {
      // lanes 0-7 poll dep A, lanes 8-15 poll dep B (if any)
      const uint32_t* f = nullptr;
      if (L == 0) {
        if (t > 0) {
          if (lane < 8)       f = f0 + (size_t)(t - 1) * 8 + lane;
          else if (lane < 16) f = f1 + (size_t)(t - 1) * 8 + (lane - 8);
        }
      } else {
        if (lane < 8)                 f = f0 + (size_t)t * 8 + lane;
        else if (t > 0 && lane < 16)  f = f1 + (size_t)(t - 1) * 8 + (lane - 8);
      }
      for (;;) {
        int ok = f ? (ld_flag_rlx(f) != 0u) : 1;
        if (__all(ok)) break;
        __builtin_amdgcn_s_sleep(1);
      }
    }
    {
      unsigned long long tx[8], th[8];
      if (L == 0 && t == 0) {
        #pragma unroll
        for (int i = 0; i < 8; ++i) tx[i] = 0ull;
      } else {
        const uint16_t* xp = (L == 0) ? (h1hist + (size_t)(t - 1) * (BATCH * H))
                                      : (h0pub  + (size_t)t       * (BATCH * H));
        const unsigned long long* ps = (const unsigned long long*)(xp + rb * H + seg * 32);
        #pragma unroll
        for (int i = 0; i < 8; ++i) tx[i] = ld_h64(ps + i);
      }
      const uint16_t* hp2 = (t == 0) ? (hfin + L * (BATCH * H))
                    : ((L == 0) ? (h0pub  + (size_t)(t - 1) * (BATCH * H))
                                : (h1hist + (size_t)(t - 1) * (BATCH * H)));
      const unsigned long long* ph = (const unsigned long long*)(hp2 + rb * H + seg * 32);
      #pragma unroll
      for (int i = 0; i < 8; ++i) th[i] = ld_h64(ph + i);
      #pragma unroll
      for (int i = 0; i < 8; ++i)
        *(unsigned long long*)(xhS + rb * 528 + seg * 32 + i * 4) = tx[i];
      #pragma unroll
      for (int i = 0; i < 8; ++i)
        *(unsigned long long*)(xhS + rb * 528 + 256 + seg * 32 + i * 4) = th[i];
    }
    __syncthreads();

    floatx4 a0 = {0.f,0.f,0.f,0.f}, a1 = a0, a2 = a0, a3 = a0;
    #pragma unroll
    for (int ks = 0; ks < 16; ++ks) {
      short8 bfv = *(const short8*)(xhS + b * 528 + ks * 32 + q4 * 8);
      a0 = mfma16(Af[0][ks], bfv, a0);
      a1 = mfma16(Af[1][ks], bfv, a1);
      a2 = mfma16(Af[2][ks], bfv, a2);
      a3 = mfma16(Af[3][ks], bfv, a3);
    }
    float hval[4];
    #pragma unroll
    for (int r = 0; r < 4; ++r) {
      const float gi = a0[r] + brg[0][r];
      const float gf = a1[r] + brg[1][r];
      const float gc = a2[r] + brg[2][r];
      const float go = a3[r] + brg[3][r];
      const float cn2 = sigm(gf) * cc[r] + sigm(gi) * tanh_f(gc);
      cc[r] = cn2;
      hval[r] = sigm(go) * tanh_f(cn2);
      hv.u16[r] = f2b(hval[r]);
    }
    uint16_t* dst = (L ? h1hist : h0pub) + (size_t)t * (BATCH * H) + b * H + jg;
    st_h64(dst, hv.u64);
    if (L == 1) {
      float* df = h1f + (size_t)t * (BATCH * H) + b * H + jg;
      #pragma unroll
      for (int r = 0; r < 4; ++r) df[r] = hval[r];
    }
    __syncthreads();
    if (tid == 0) st_flag_rel((L ? f1 : f0) + (size_t)t * 8 + q, 1u);
  }
}

// =====================================================================
// Phase D
// =====================================================================
__global__ __launch_bounds__(256) void out_proj(
    const float* __restrict__ h1f, const float* __restrict__ linW,
    const float* __restrict__ linb, float* __restrict__ out)
{
  const int idx = blockIdx.x * 256 + threadIdx.x;
  if (idx >= DSTEPS * BATCH * 3) return;
  const int v = idx % 3;
  const int tb = idx / 3;
  const float* hrow = h1f + (size_t)tb * H;
  const float* wrow = linW + (size_t)v * H;
  float s = linb[v];
  for (int k = 0; k < H; ++k) s += hrow[k] * wrow[k];
  out[idx] = s;
}

// =====================================================================
extern "C" void kernel_launch(void* const* d_in, const int* in_sizes, int n_in,
                              void* d_out, int out_size, void* d_ws, size_t ws_size,
                              hipStream_t stream) {
  (void)in_sizes; (void)n_in; (void)out_size;
  const float* cnn   = (const float*)d_in[0];
  const float* WihF  = (const float*)d_in[1];
  const float* WhhF  = (const float*)d_in[2];
  const float* bF    = (const float*)d_in[3];
  const float* WihB  = (const float*)d_in[4];
  const float* WhhB  = (const float*)d_in[5];
  const float* bB    = (const float*)d_in[6];
  const float* Wih0  = (const float*)d_in[7];
  const float* Whh0  = (const float*)d_in[8];
  const float* b0    = (const float*)d_in[9];
  const float* Wih1  = (const float*)d_in[10];
  const float* Whh1  = (const float*)d_in[11];
  const float* b1    = (const float*)d_in[12];
  const float* linW  = (const float*)d_in[13];
  const float* linb  = (const float*)d_in[14];

  const size_t XG_ELEMS = (size_t)TSEQ * BATCH * FH;
  const size_t SMALL    = 4395008;
  const int xg_f32 = (ws_size >= 2 * XG_ELEMS * 4 + SMALL) ? 1 : 0;
  const size_t S = XG_ELEMS * (xg_f32 ? 4 : 2);

  uint8_t* ws = (uint8_t*)d_ws;
  void*     XgF    = (void*)(ws);
  void*     XgB    = (void*)(ws + S);
  uint8_t*  base   = ws + 2 * S;
  uint16_t* hpub   = (uint16_t*)(base);              // 65536
  uint16_t* hfin   = (uint16_t*)(base + 65536);      // 32768
  float*    cfin   = (float*)(base + 98304);         // 65536
  uint16_t* h0pub  = (uint16_t*)(base + 163840);     // 1 MB
  uint16_t* h1hist = (uint16_t*)(base + 1212416);    // 1 MB
  float*    h1f    = (float*)(base + 2260992);       // 2 MB
  uint8_t*  ctrl   = base + 4358144;                 // zeroed flag region
  uint32_t* encflags = (uint32_t*)(ctrl);            // 2*512*8*4 = 32768
  uint32_t* decf0    = (uint32_t*)(ctrl + 32768);    // 64*8*4 = 2048
  uint32_t* decf1    = (uint32_t*)(ctrl + 34816);    // 2048

  hipMemsetAsync(ctrl, 0, 36864, stream);

  gemm_xw<<<dim3(256, 16), 256, 0, stream>>>(cnn, WihF, bF, XgF, xg_f32);
  gemm_xw<<<dim3(256, 16), 256, 0, stream>>>(cnn, WihB, bB, XgB, xg_f32);
  enc_rnn<<<16, 256, 0, stream>>>(XgF, XgB, xg_f32, WhhF, WhhB,
                                  hpub, encflags, hfin, cfin);
  dec_rnn<<<16, 256, 0, stream>>>(Wih0, Whh0, b0, Wih1, Whh1, b1,
                                  hfin, cfin, h0pub, h1hist, h1f,
                                  decf0, decf1);
  out_proj<<<24, 256, 0, stream>>>(h1f, linW, linb, (float*)d_out);
}

// Round 5
// 2588.552 us; speedup vs baseline: 1.6087x; 1.1332x over previous
//
#include <hip/hip_runtime.h>
#include <stdint.h>
#include <stddef.h>

// ---------- types / helpers ----------
typedef __attribute__((ext_vector_type(8))) short  short8;   // 8 bf16 (4 VGPRs)
typedef __attribute__((ext_vector_type(4))) float  floatx4;  // MFMA acc
typedef unsigned long long u64;

#define SENT 0xAAAAAAAAAAAAAAAAull   // ws poison pattern = our sentinel

static __device__ __forceinline__ float b2f(uint16_t h) {
  union { uint32_t u; float f; } v; v.u = ((uint32_t)h) << 16; return v.f;
}
static __device__ __forceinline__ uint16_t f2b(float f) {
  union { float f; uint32_t u; } v; v.f = f;
  uint32_t u = v.u;
  uint32_t r = u + 0x7FFFu + ((u >> 16) & 1u);   // RNE
  return (uint16_t)(r >> 16);
}
static __device__ __forceinline__ float sigm(float x)  { return 1.0f / (1.0f + __expf(-x)); }
static __device__ __forceinline__ float tanh_f(float x){ return 1.0f - 2.0f / (1.0f + __expf(2.0f * x)); }

static __device__ __forceinline__ floatx4 mfma16(short8 a, short8 b, floatx4 c) {
  return __builtin_amdgcn_mfma_f32_16x16x32_bf16(a, b, c, 0, 0, 0);
}
static __device__ __forceinline__ short8 cvt8(const float* p) {
  short8 r;
  #pragma unroll
  for (int i = 0; i < 8; ++i) r[i] = (short)f2b(p[i]);
  return r;
}
// agent-scope primitives (proven in rounds 2/4)
static __device__ __forceinline__ u64 ld_h64(const u64* p) {
  return __hip_atomic_load(p, __ATOMIC_RELAXED, __HIP_MEMORY_SCOPE_AGENT);
}
static __device__ __forceinline__ void st_h64(uint16_t* p, u64 v) {
  __hip_atomic_store((u64*)p, v, __ATOMIC_RELAXED, __HIP_MEMORY_SCOPE_AGENT);
}
// poll 8 consecutive u64 words until none equals the sentinel
static __device__ __forceinline__ void poll8(const u64* p, u64* o) {
  for (;;) {
    bool ok = true;
    #pragma unroll
    for (int i = 0; i < 8; ++i) { o[i] = ld_h64(p + i); ok &= (o[i] != SENT); }
    if (ok) break;
    __builtin_amdgcn_s_sleep(1);
  }
}

#define H 256
#define FH 1024
#define BATCH 32
#define TSEQ 512
#define DSTEPS 64
#define ERING 8          // encoder h-slot ring depth

// =====================================================================
// Phase A GEMM (unchanged — correct since round 2)
// =====================================================================
__global__ __launch_bounds__(256) void gemm_xw(
    const float* __restrict__ A, const float* __restrict__ W,
    const float* __restrict__ bias, void* __restrict__ Cout, int out_f32)
{
  const int K = 1024, N = 1024;
  __shared__ uint16_t Ah[64 * 40], Al[64 * 40];
  __shared__ uint16_t Wh[64 * 40], Wl[64 * 40];
  const int m0 = blockIdx.x * 64;
  const int n0 = blockIdx.y * 64;
  const int tid = threadIdx.x;
  const int lane = tid & 63, w = tid >> 6;
  const int wm = w & 1, wn = w >> 1;
  const int l15 = lane & 15, q4 = lane >> 4;
  const int ldrow = tid >> 2, ldk = (tid & 3) * 8;

  floatx4 acc[2][2];
  for (int i = 0; i < 2; ++i) for (int j = 0; j < 2; ++j) acc[i][j] = (floatx4){0.f,0.f,0.f,0.f};

  for (int kb = 0; kb < K; kb += 32) {
    float aa[8], ww[8];
    {
      const float4* ap = (const float4*)(A + (size_t)(m0 + ldrow) * K + kb + ldk);
      const float4* wp = (const float4*)(W + (size_t)(n0 + ldrow) * K + kb + ldk);
      *(float4*)(aa) = ap[0]; *(float4*)(aa + 4) = ap[1];
      *(float4*)(ww) = wp[0]; *(float4*)(ww + 4) = wp[1];
    }
    short8 ah, al, wh, wl;
    #pragma unroll
    for (int i = 0; i < 8; ++i) {
      uint16_t h = f2b(aa[i]); ah[i] = (short)h; al[i] = (short)f2b(aa[i] - b2f(h));
      uint16_t g = f2b(ww[i]); wl[i] = (short)f2b(ww[i] - b2f(f2b(ww[i]) ? 0 : 0)); // placeholder (overwritten)
      wh[i] = (short)f2b(ww[i]); wl[i] = (short)f2b(ww[i] - b2f((uint16_t)wh[i]));
    }
    __syncthreads();
    *(short8*)(Ah + ldrow * 40 + ldk) = ah;
    *(short8*)(Al + ldrow * 40 + ldk) = al;
    *(short8*)(Wh + ldrow * 40 + ldk) = wh;
    *(short8*)(Wl + ldrow * 40 + ldk) = wl;
    __syncthreads();
    short8 afh[2], afl[2], bfh[2], bfl[2];
    #pragma unroll
    for (int mt = 0; mt < 2; ++mt) {
      afh[mt] = *(const short8*)(Ah + (wm * 32 + mt * 16 + l15) * 40 + q4 * 8);
      afl[mt] = *(const short8*)(Al + (wm * 32 + mt * 16 + l15) * 40 + q4 * 8);
    }
    #pragma unroll
    for (int nt = 0; nt < 2; ++nt) {
      bfh[nt] = *(const short8*)(Wh + (wn * 32 + nt * 16 + l15) * 40 + q4 * 8);
      bfl[nt] = *(const short8*)(Wl + (wn * 32 + nt * 16 + l15) * 40 + q4 * 8);
    }
    #pragma unroll
    for (int mt = 0; mt < 2; ++mt)
      #pragma unroll
      for (int nt = 0; nt < 2; ++nt) {
        acc[mt][nt] = mfma16(afh[mt], bfh[nt], acc[mt][nt]);
        acc[mt][nt] = mfma16(afh[mt], bfl[nt], acc[mt][nt]);
        acc[mt][nt] = mfma16(afl[mt], bfh[nt], acc[mt][nt]);
      }
  }
  #pragma unroll
  for (int mt = 0; mt < 2; ++mt)
    #pragma unroll
    for (int nt = 0; nt < 2; ++nt) {
      const int col = n0 + wn * 32 + nt * 16 + l15;
      const float bv = bias[col];
      #pragma unroll
      for (int r = 0; r < 4; ++r) {
        const int row = m0 + wm * 32 + mt * 16 + q4 * 4 + r;
        const float v = acc[mt][nt][r] + bv;
        if (out_f32) ((float*)Cout)[(size_t)row * N + col] = v;
        else         ((uint16_t*)Cout)[(size_t)row * N + col] = f2b(v);
      }
    }
}

// =====================================================================
// Phase B: encoder recurrence. Grid = 16 WGs: d = blk>>3, q = blk&7.
// Sync: data-is-the-flag. h published per-thread as relaxed u64 into an
// 8-deep per-step slot ring (pre-poisoned 0xAA); consumers poll their own
// payload words until != SENT. Consumer at step s re-poisons its published
// slice of slot s-2 (safe: slot s-1 visible from all WGs => s-2 fully
// consumed; per-step barrier vmcnt(0) drain bounds store completion).
// Single barrier/step via parity double-buffered LDS.
// =====================================================================
__global__ __launch_bounds__(256, 1) void enc_rnn(
    const void* __restrict__ XgF, const void* __restrict__ XgB, int xg_f32,
    const float* __restrict__ WhhF, const float* __restrict__ WhhB,
    uint16_t* __restrict__ hslots,    // [2 dir][ERING][32][256] bf16, poisoned
    uint16_t* __restrict__ hfin, float* __restrict__ cfin)
{
  const int d = blockIdx.x >> 3, q = blockIdx.x & 7;
  const void*  Xg  = d ? XgB : XgF;
  const float* Whh = d ? WhhB : WhhF;
  uint16_t* hsl = hslots + d * (ERING * BATCH * H);
  const int jOff = q * 32;
  const int tid = threadIdx.x, lane = tid & 63, w = tid >> 6;
  const int tt = w & 1, nt = w >> 1, l15 = lane & 15, q4 = lane >> 4;
  const int b = nt * 16 + l15;
  const int jg = jOff + tt * 16 + q4 * 4;

  __shared__ uint16_t hS[2][32 * 264];
  __shared__ float    xgS[2][32 * 132];

  short8 Af[4][8];
  #pragma unroll
  for (int g = 0; g < 4; ++g) {
    const int grow = g * H + jOff + tt * 16 + l15;
    #pragma unroll
    for (int ks = 0; ks < 8; ++ks)
      Af[g][ks] = cvt8(Whh + (size_t)grow * H + ks * 32 + q4 * 8);
  }
  for (int i = tid; i < 32 * 264; i += 256) hS[0][i] = 0;   // h_0 = 0

  float cc[4] = {0.f, 0.f, 0.f, 0.f};
  union HV { uint16_t u16[4]; u64 v; } hv; hv.v = 0ull;
  const int rb = tid >> 3, seg = tid & 7;
  const int cp = seg * 16;
  const int gge = cp >> 5, jj = cp & 31;

  for (int s = 0; s < TSEQ; ++s) {
    const int t = d ? (TSEQ - 1 - s) : s;
    const int p = s & 1;
    // stage this step's Xg slice early
    float xv[16];
    {
      const size_t base = (size_t)(t * BATCH + rb) * FH + gge * H + jOff + jj;
      if (xg_f32) {
        const float4* xs = (const float4*)((const float*)Xg + base);
        *(float4*)(xv) = xs[0]; *(float4*)(xv + 4) = xs[1];
        *(float4*)(xv + 8) = xs[2]; *(float4*)(xv + 12) = xs[3];
      } else {
        const uint16_t* xs = (const uint16_t*)Xg + base;
        #pragma unroll
        for (int i = 0; i < 16; ++i) xv[i] = b2f(xs[i]);
      }
    }

    if (s > 0) {
      u64 tmp[8];
      const u64* ps = (const u64*)(hsl + ((s - 1) & (ERING - 1)) * (BATCH * H) + rb * H + seg * 32);
      poll8(ps, tmp);
      #pragma unroll
      for (int i = 0; i < 8; ++i)
        *(u64*)(hS[p] + rb * 264 + seg * 32 + i * 4) = tmp[i];
    }
    if (s >= 2)   // re-poison own slice of slot s-2 for ring reuse
      st_h64(hsl + ((s - 2) & (ERING - 1)) * (BATCH * H) + b * H + jg, SENT);
    #pragma unroll
    for (int i = 0; i < 16; ++i) xgS[p][rb * 132 + cp + i] = xv[i];
    __syncthreads();

    floatx4 a0 = {0.f,0.f,0.f,0.f}, a1 = a0, a2 = a0, a3 = a0;
    #pragma unroll
    for (int ks = 0; ks < 8; ++ks) {
      short8 bfv = *(const short8*)(hS[p] + b * 264 + ks * 32 + q4 * 8);
      a0 = mfma16(Af[0][ks], bfv, a0);
      a1 = mfma16(Af[1][ks], bfv, a1);
      a2 = mfma16(Af[2][ks], bfv, a2);
      a3 = mfma16(Af[3][ks], bfv, a3);
    }
    #pragma unroll
    for (int r = 0; r < 4; ++r) {
      const int jl = tt * 16 + q4 * 4 + r;
      const float gi = a0[r] + xgS[p][b * 132 +      jl];
      const float gf = a1[r] + xgS[p][b * 132 + 32 + jl];
      const float gc = a2[r] + xgS[p][b * 132 + 64 + jl];
      const float go = a3[r] + xgS[p][b * 132 + 96 + jl];
      const float cn2 = sigm(gf) * cc[r] + sigm(gi) * tanh_f(gc);
      cc[r] = cn2;
      hv.u16[r] = f2b(sigm(go) * tanh_f(cn2));
    }
    st_h64(hsl + (s & (ERING - 1)) * (BATCH * H) + b * H + jg, hv.v);
  }
  #pragma unroll
  for (int r = 0; r < 4; ++r) {
    hfin[d * (BATCH * H) + b * H + jg + r] = hv.u16[r];   // kernel boundary
    cfin[d * (BATCH * H) + b * H + jg + r] = cc[r];
  }
}

// =====================================================================
// Phase C: decoder, 2 layers x 64 steps. Grid = 16 WGs: L = blk>>3, q = blk&7.
// Write-once per-step slots (poisoned), data-is-the-flag polling.
// Poll order: own-layer h (early dep) then cross-layer x (late dep).
// =====================================================================
__global__ __launch_bounds__(256, 1) void dec_rnn(
    const float* __restrict__ Wih0, const float* __restrict__ Whh0, const float* __restrict__ bb0,
    const float* __restrict__ Wih1, const float* __restrict__ Whh1, const float* __restrict__ bb1,
    const uint16_t* __restrict__ hfin, const float* __restrict__ cfin,
    uint16_t* __restrict__ h0slots,  // [64][32][256] bf16, poisoned
    uint16_t* __restrict__ h1slots,  // [64][32][256] bf16, poisoned
    float*    __restrict__ h1f)      // [64][32][256] f32 (plain)
{
  const int L = blockIdx.x >> 3, q = blockIdx.x & 7;
  const float* Wih = L ? Wih1 : Wih0;
  const float* Whh = L ? Whh1 : Whh0;
  const float* bs  = L ? bb1 : bb0;
  const int jOff = q * 32;
  const int tid = threadIdx.x, lane = tid & 63, w = tid >> 6;
  const int tt = w & 1, nt = w >> 1, l15 = lane & 15, q4 = lane >> 4;
  const int b = nt * 16 + l15;
  const int jg = jOff + tt * 16 + q4 * 4;

  __shared__ uint16_t xhS[2][32 * 528];

  short8 Af[4][16];
  #pragma unroll
  for (int g = 0; g < 4; ++g) {
    const int grow = g * H + jOff + tt * 16 + l15;
    #pragma unroll
    for (int ks = 0; ks < 8; ++ks) {
      Af[g][ks]     = cvt8(Wih + (size_t)grow * H + ks * 32 + q4 * 8);
      Af[g][8 + ks] = cvt8(Whh + (size_t)grow * H + ks * 32 + q4 * 8);
    }
  }
  float brg[4][4];
  #pragma unroll
  for (int g = 0; g < 4; ++g)
    #pragma unroll
    for (int r = 0; r < 4; ++r)
      brg[g][r] = bs[g * H + jOff + tt * 16 + q4 * 4 + r];

  float cc[4];
  #pragma unroll
  for (int r = 0; r < 4; ++r) cc[r] = cfin[L * (BATCH * H) + b * H + jg + r];

  const int rb = tid >> 3, seg = tid & 7;
  const size_t off = (size_t)rb * H + seg * 32;
  union HV { uint16_t u16[4]; u64 v; } hv; hv.v = 0ull;

  for (int t = 0; t < DSTEPS; ++t) {
    const int p = t & 1;
    u64 tx[8], th[8];
    // own-layer previous h (early dependency)
    if (t == 0) {
      const u64* ph = (const u64*)(hfin + L * (BATCH * H) + off);
      #pragma unroll
      for (int i = 0; i < 8; ++i) th[i] = ph[i];       // plain, kernel boundary
    } else {
      const uint16_t* hb = (L ? h1slots : h0slots) + (size_t)(t - 1) * (BATCH * H);
      poll8((const u64*)(hb + off), th);
    }
    // cross-layer x (late dependency)
    if (L == 0) {
      if (t == 0) {
        #pragma unroll
        for (int i = 0; i < 8; ++i) tx[i] = 0ull;
      } else {
        poll8((const u64*)(h1slots + (size_t)(t - 1) * (BATCH * H) + off), tx);
      }
    } else {
      poll8((const u64*)(h0slots + (size_t)t * (BATCH * H) + off), tx);
    }
    #pragma unroll
    for (int i = 0; i < 8; ++i) {
      *(u64*)(xhS[p] + rb * 528 + seg * 32 + i * 4) = tx[i];
      *(u64*)(xhS[p] + rb * 528 + 256 + seg * 32 + i * 4) = th[i];
    }
    __syncthreads();

    floatx4 a0 = {0.f,0.f,0.f,0.f}, a1 = a0, a2 = a0, a3 = a0;
    #pragma unroll
    for (int ks = 0; ks < 16; ++ks) {
      short8 bfv = *(const short8*)(xhS[p] + b * 528 + ks * 32 + q4 * 8);
      a0 = mfma16(Af[0][ks], bfv, a0);
      a1 = mfma16(Af[1][ks], bfv, a1);
      a2 = mfma16(Af[2][ks], bfv, a2);
      a3 = mfma16(Af[3][ks], bfv, a3);
    }
    float hval[4];
    #pragma unroll
    for (int r = 0; r < 4; ++r) {
      const float gi = a0[r] + brg[0][r];
      const float gf = a1[r] + brg[1][r];
      const float gc = a2[r] + brg[2][r];
      const float go = a3[r] + brg[3][r];
      const float cn2 = sigm(gf) * cc[r] + sigm(gi) * tanh_f(gc);
      cc[r] = cn2;
      hval[r] = sigm(go) * tanh_f(cn2);
      hv.u16[r] = f2b(hval[r]);
    }
    st_h64((L ? h1slots : h0slots) + (size_t)t * (BATCH * H) + b * H + jg, hv.v);
    if (L == 1) {
      float* df = h1f + (size_t)t * (BATCH * H) + b * H + jg;
      #pragma unroll
      for (int r = 0; r < 4; ++r) df[r] = hval[r];
    }
  }
}

// =====================================================================
// Phase D
// =====================================================================
__global__ __launch_bounds__(256) void out_proj(
    const float* __restrict__ h1f, const float* __restrict__ linW,
    const float* __restrict__ linb, float* __restrict__ out)
{
  const int idx = blockIdx.x * 256 + threadIdx.x;
  if (idx >= DSTEPS * BATCH * 3) return;
  const int v = idx % 3;
  const int tb = idx / 3;
  const float* hrow = h1f + (size_t)tb * H;
  const float* wrow = linW + (size_t)v * H;
  float s = linb[v];
  for (int k = 0; k < H; ++k) s += hrow[k] * wrow[k];
  out[idx] = s;
}

// =====================================================================
extern "C" void kernel_launch(void* const* d_in, const int* in_sizes, int n_in,
                              void* d_out, int out_size, void* d_ws, size_t ws_size,
                              hipStream_t stream) {
  (void)in_sizes; (void)n_in; (void)out_size;
  const float* cnn   = (const float*)d_in[0];
  const float* WihF  = (const float*)d_in[1];
  const float* WhhF  = (const float*)d_in[2];
  const float* bF    = (const float*)d_in[3];
  const float* WihB  = (const float*)d_in[4];
  const float* WhhB  = (const float*)d_in[5];
  const float* bB    = (const float*)d_in[6];
  const float* Wih0  = (const float*)d_in[7];
  const float* Whh0  = (const float*)d_in[8];
  const float* b0    = (const float*)d_in[9];
  const float* Wih1  = (const float*)d_in[10];
  const float* Whh1  = (const float*)d_in[11];
  const float* b1    = (const float*)d_in[12];
  const float* linW  = (const float*)d_in[13];
  const float* linb  = (const float*)d_in[14];

  const size_t XG_ELEMS = (size_t)TSEQ * BATCH * FH;   // 16 Mi elems / dir
  // small region: hslotsE 262144 | h0slots 1 MB | h1slots 1 MB | hfin 32K | cfin 64K
  const size_t SMALL = 2457600;
  const int xg_f32 = (ws_size >= 2 * XG_ELEMS * 4 + SMALL) ? 1 : 0;
  const size_t S = XG_ELEMS * (xg_f32 ? 4 : 2);

  uint8_t* ws = (uint8_t*)d_ws;
  void*     XgF    = (void*)(ws);
  void*     XgB    = (void*)(ws + S);
  float*    h1f    = (float*)(ws + S);                 // overlaps XgB: dead after enc
  uint8_t*  base   = ws + 2 * S;
  uint16_t* hslotsE = (uint16_t*)(base);               // 2*8*8192*2   = 262144
  uint16_t* h0slots = (uint16_t*)(base + 262144);      // 64*8192*2    = 1048576
  uint16_t* h1slots = (uint16_t*)(base + 1310720);     // 1048576  (poison end 2359296)
  uint16_t* hfin    = (uint16_t*)(base + 2359296);     // 32768
  float*    cfin    = (float*)(base + 2392064);        // 65536 (end 2457600)

  // sentinel-poison all exchange slots (required every launch, incl. replays)
  hipMemsetAsync(base, 0xAA, 2359296, stream);

  gemm_xw<<<dim3(256, 16), 256, 0, stream>>>(cnn, WihF, bF, XgF, xg_f32);
  gemm_xw<<<dim3(256, 16), 256, 0, stream>>>(cnn, WihB, bB, XgB, xg_f32);
  enc_rnn<<<16, 256, 0, stream>>>(XgF, XgB, xg_f32, WhhF, WhhB,
                                  hslotsE, hfin, cfin);
  dec_rnn<<<16, 256, 0, stream>>>(Wih0, Whh0, b0, Wih1, Whh1, b1,
                                  hfin, cfin, h0slots, h1slots, h1f);
  out_proj<<<24, 256, 0, stream>>>(h1f, linW, linb, (float*)d_out);
}